// Round 18
// baseline (185.546 us; speedup 1.0000x reference)
//
#include <hip/hip_runtime.h>
#include <hip/hip_fp16.h>
#include <math.h>

#define NEG_SLOPE 0.2f
#define EPS_SM 1e-8f
#define EPS_LN 1e-5f
#define PAD 16          // one global counter per 64B line
#define BSH 8           // bucket = dst >> 8  (256 nodes/bucket)
#define NBMAX 512       // max buckets (n <= 131072)
#define CHUNK 2048      // edges per bhist/esc block
#define CHUNK1 1024     // edges per pass1 block (512 thr x 2 edges)

// round-to-nearest bf16 pair pack: returns (bf16(b)<<16) | bf16(a)
__device__ inline unsigned bf16pair(float a, float b)
{
    unsigned ua = __float_as_uint(a), ub = __float_as_uint(b);
    ua = (ua + 0x7fffu + ((ua >> 16) & 1u)) >> 16;
    ub = (ub + 0x7fffu + ((ub >> 16) & 1u)) >> 16;
    return ua | (ub << 16);
}

// ---------------------------------------------------------------------------
// Kernel 1 (triple-fused, 256 thr):
//  blocks [0, nbNode):                 h = x @ W_node + a_src/a_dst projections
//  blocks [nbNode, nbNode+nchunk):     bucket histogram over dst
//  blocks [nbNode+nchunk, +nesc):      esc16 = ea @ W_edge  (pure stream, f16x4)
// The esc stream (BW-bound) co-schedules with the GEMM blocks (VALU-bound).
// ---------------------------------------------------------------------------
__global__ __launch_bounds__(256) void k_node_hist_esc(
    const float* __restrict__ x, const float* __restrict__ Wn,
    const float* __restrict__ attn_src, const float* __restrict__ attn_dst,
    __half* __restrict__ h16, float* __restrict__ a_src, float* __restrict__ a_dst,
    int n, const int* __restrict__ dst, int* __restrict__ gbcnt, int E,
    int nbNode, int nchunk,
    const float* __restrict__ ea, const float* __restrict__ We,
    __half* __restrict__ esc16)
{
    __shared__ float Ws[64][64];   // W[k][col]  (hist: cnt[]; esc: Wes[])
    __shared__ float xs[64][64];   // x[r][k]
    const int tid = threadIdx.x;

    if (blockIdx.x >= nbNode + nchunk) {
        // ---- esc stream branch: esc16[e] = f16x4(ea[e] @ We) ----
        float* Wes = (float*)Ws;
        if (tid < 64) Wes[tid] = We[tid];
        __syncthreads();
        const int e0 = (blockIdx.x - nbNode - nchunk) * CHUNK;
        const int ce = min(CHUNK, E - e0);
        for (int j = tid; j < ce; j += 256) {
            int e = e0 + j;
            const float4* ea4 = (const float4*)(ea + (size_t)e * 16);
            float4 q0 = ea4[0], q1 = ea4[1], q2 = ea4[2], q3 = ea4[3];
            float eav[16] = {q0.x, q0.y, q0.z, q0.w, q1.x, q1.y, q1.z, q1.w,
                             q2.x, q2.y, q2.z, q2.w, q3.x, q3.y, q3.z, q3.w};
            float esc[4] = {0.f, 0.f, 0.f, 0.f};
            #pragma unroll
            for (int k = 0; k < 16; ++k) {
                #pragma unroll
                for (int hh = 0; hh < 4; ++hh) esc[hh] += eav[k] * Wes[k * 4 + hh];
            }
            __half2 p01 = __floats2half2_rn(esc[0], esc[1]);
            __half2 p23 = __floats2half2_rn(esc[2], esc[3]);
            uint2 pk = make_uint2(*reinterpret_cast<unsigned*>(&p01),
                                  *reinterpret_cast<unsigned*>(&p23));
            *(uint2*)&esc16[(size_t)e * 4] = pk;
        }
        return;
    }

    if (blockIdx.x >= nbNode) {
        // ---- bucket histogram branch ----
        int* cnt = (int*)Ws;
        for (int i = tid; i < NBMAX; i += 256) cnt[i] = 0;
        __syncthreads();
        const int e0 = (blockIdx.x - nbNode) * CHUNK;
        const int ce = min(CHUNK, E - e0);
        for (int j = tid; j < ce; j += 256)
            atomicAdd(&cnt[((unsigned)dst[e0 + j]) >> BSH], 1);
        __syncthreads();
        for (int b = tid; b < NBMAX; b += 256)
            if (cnt[b] > 0) atomicAdd(&gbcnt[b * PAD], cnt[b]);
        return;
    }

    // ---- node GEMM branch ----
    const int row0 = blockIdx.x * 64;

    const float4* Wn4 = (const float4*)Wn;
    #pragma unroll
    for (int i = tid; i < 1024; i += 256) {
        float4 v = Wn4[i];
        *(float4*)&Ws[i >> 4][(i & 15) * 4] = v;
    }
    const float4* x4 = (const float4*)x;
    #pragma unroll
    for (int i = tid; i < 1024; i += 256) {
        int r  = i >> 4;
        int gr = row0 + r;
        float4 v = (gr < n) ? x4[(size_t)gr * 16 + (i & 15)]
                            : make_float4(0.f, 0.f, 0.f, 0.f);
        *(float4*)&xs[r][(i & 15) * 4] = v;
    }
    __syncthreads();

    const int c4 = tid & 15;
    const int r4 = tid >> 4;

    float4 acc0 = make_float4(0.f, 0.f, 0.f, 0.f);
    float4 acc1 = make_float4(0.f, 0.f, 0.f, 0.f);
    float4 acc2 = make_float4(0.f, 0.f, 0.f, 0.f);
    float4 acc3 = make_float4(0.f, 0.f, 0.f, 0.f);

    #pragma unroll 8
    for (int k = 0; k < 64; ++k) {
        float4 w = *(const float4*)&Ws[k][c4 * 4];
        float x0 = xs[r4     ][k];
        float x1 = xs[r4 + 16][k];
        float x2 = xs[r4 + 32][k];
        float x3 = xs[r4 + 48][k];
        acc0.x += x0 * w.x; acc0.y += x0 * w.y; acc0.z += x0 * w.z; acc0.w += x0 * w.w;
        acc1.x += x1 * w.x; acc1.y += x1 * w.y; acc1.z += x1 * w.z; acc1.w += x1 * w.w;
        acc2.x += x2 * w.x; acc2.y += x2 * w.y; acc2.z += x2 * w.z; acc2.w += x2 * w.w;
        acc3.x += x3 * w.x; acc3.y += x3 * w.y; acc3.z += x3 * w.z; acc3.w += x3 * w.w;
    }

    const float4 asw = *(const float4*)&attn_src[c4 * 4];
    const float4 adw = *(const float4*)&attn_dst[c4 * 4];
    const int hh = c4 >> 2;
    const bool writer = (c4 & 3) == 0;

    float4 accs[4] = {acc0, acc1, acc2, acc3};
    #pragma unroll
    for (int j = 0; j < 4; ++j) {
        int gr = row0 + r4 + 16 * j;
        if (gr < n) {
            __half2 p0 = __floats2half2_rn(accs[j].x, accs[j].y);
            __half2 p1 = __floats2half2_rn(accs[j].z, accs[j].w);
            uint2 pk = make_uint2(*reinterpret_cast<unsigned*>(&p0),
                                  *reinterpret_cast<unsigned*>(&p1));
            *(uint2*)&h16[(size_t)gr * 64 + c4 * 4] = pk;
            float ps = accs[j].x * asw.x + accs[j].y * asw.y +
                       accs[j].z * asw.z + accs[j].w * asw.w;
            float pd = accs[j].x * adw.x + accs[j].y * adw.y +
                       accs[j].z * adw.z + accs[j].w * adw.w;
            ps += __shfl_xor(ps, 1, 64); ps += __shfl_xor(ps, 2, 64);
            pd += __shfl_xor(pd, 1, 64); pd += __shfl_xor(pd, 2, 64);
            if (writer) {
                a_src[(size_t)gr * 4 + hh] = ps;
                a_dst[(size_t)gr * 4 + hh] = pd;
            }
        } else {
            float ps = 0.f, pd = 0.f;
            ps += __shfl_xor(ps, 1, 64); ps += __shfl_xor(ps, 2, 64);
            pd += __shfl_xor(pd, 1, 64); pd += __shfl_xor(pd, 2, 64);
        }
    }
}

// ---------------------------------------------------------------------------
// Kernel 2: exclusive scan of 512 bucket counts (one wave).
// ---------------------------------------------------------------------------
__global__ void k_bscan(const int* __restrict__ gbcnt,
                        int* __restrict__ bstart, int* __restrict__ bcount,
                        int* __restrict__ bcur)
{
    int lane = threadIdx.x;   // 64 threads
    int c[8]; int s = 0;
    #pragma unroll
    for (int j = 0; j < 8; ++j) { c[j] = gbcnt[(lane * 8 + j) * PAD]; s += c[j]; }
    int incl = s;
    #pragma unroll
    for (int off = 1; off < 64; off <<= 1) {
        int u = __shfl_up(incl, off, 64);
        if (lane >= off) incl += u;
    }
    int run = incl - s;
    #pragma unroll
    for (int j = 0; j < 8; ++j) {
        int b = lane * 8 + j;
        bstart[b] = run;
        bcount[b] = c[j];
        bcur[b * PAD] = run;
        run += c[j];
    }
}

// ---------------------------------------------------------------------------
// Kernel 3: bucket-grouped scatter + weight computation from precomputed
// esc16 (NO ea stream here — reads are tiny: src/dst/esc16 + L2-hot
// a-gathers). 512 threads, 2 edges/thread. w = exp(lrelu(as+esc+ad)),
// packed bf16x4. Record: int4 { src, bf16x2(w0,w1), bf16x2(w2,w3), dst }.
// ---------------------------------------------------------------------------
__global__ __launch_bounds__(512) void k_pass1(
    const int* __restrict__ src, const int* __restrict__ dst,
    const __half* __restrict__ esc16,
    const float* __restrict__ a_src, const float* __restrict__ a_dst,
    int* __restrict__ bcur, int4* __restrict__ rec_out,
    unsigned char* __restrict__ dl8_out, int E)
{
    __shared__ int cnt[NBMAX];      // 2KB
    __shared__ int gpos[NBMAX];     // 2KB
    const int tid = threadIdx.x;
    if (tid < NBMAX) cnt[tid] = 0;
    __syncthreads();

    const int e0 = blockIdx.x * CHUNK1;
    int d[2], s[2], rk[2];
    #pragma unroll
    for (int j = 0; j < 2; ++j) {
        int e = e0 + j * 512 + tid;
        bool v = e < E;
        d[j] = v ? dst[e] : -1;
        s[j] = v ? src[e] : 0;
    }

    #pragma unroll
    for (int j = 0; j < 2; ++j)
        rk[j] = (d[j] >= 0) ? atomicAdd(&cnt[((unsigned)d[j]) >> BSH], 1) : 0;

    float4 as4[2], ad4[2];
    uint2 ev[2];
    #pragma unroll
    for (int j = 0; j < 2; ++j) {
        int e = e0 + j * 512 + tid;
        as4[j] = (d[j] >= 0) ? *(const float4*)(a_src + (size_t)s[j] * 4)
                             : make_float4(0.f, 0.f, 0.f, 0.f);
        ad4[j] = (d[j] >= 0) ? *(const float4*)(a_dst + (size_t)d[j] * 4)
                             : make_float4(0.f, 0.f, 0.f, 0.f);
        ev[j]  = (d[j] >= 0) ? *(const uint2*)&esc16[(size_t)e * 4]
                             : make_uint2(0, 0);
    }

    int ry[2], rz[2];
    #pragma unroll
    for (int j = 0; j < 2; ++j) {
        if (d[j] < 0) { ry[j] = 0; rz[j] = 0; continue; }
        float2 e01 = __half22float2(*reinterpret_cast<__half2*>(&ev[j].x));
        float2 e23 = __half22float2(*reinterpret_cast<__half2*>(&ev[j].y));
        float a0 = as4[j].x + e01.x + ad4[j].x;
        float a1 = as4[j].y + e01.y + ad4[j].y;
        float a2 = as4[j].z + e23.x + ad4[j].z;
        float a3 = as4[j].w + e23.y + ad4[j].w;
        a0 = (a0 >= 0.f) ? a0 : NEG_SLOPE * a0;
        a1 = (a1 >= 0.f) ? a1 : NEG_SLOPE * a1;
        a2 = (a2 >= 0.f) ? a2 : NEG_SLOPE * a2;
        a3 = (a3 >= 0.f) ? a3 : NEG_SLOPE * a3;
        ry[j] = (int)bf16pair(__expf(a0), __expf(a1));
        rz[j] = (int)bf16pair(__expf(a2), __expf(a3));
    }
    __syncthreads();

    if (tid < NBMAX) {
        int c = cnt[tid];
        if (c > 0) gpos[tid] = atomicAdd(&bcur[tid * PAD], c);
    }
    __syncthreads();

    #pragma unroll
    for (int j = 0; j < 2; ++j) {
        if (d[j] < 0) continue;
        int g = gpos[((unsigned)d[j]) >> BSH] + rk[j];
        rec_out[g] = make_int4(s[j], ry[j], rz[j], d[j]);
        dl8_out[g] = (unsigned char)(d[j] & 255);
    }
}

// ---------------------------------------------------------------------------
// Kernel 4: per-bucket counting sort to per-node-contiguous order (pure
// permutation — weights already in the record). Emits recs2 + nstart/ndeg.
// ---------------------------------------------------------------------------
__global__ __launch_bounds__(1024) void k_bin(
    const int* __restrict__ bstart, const int* __restrict__ bcount,
    const int4* __restrict__ recs, const unsigned char* __restrict__ dl8,
    int4* __restrict__ recs2, int* __restrict__ nstart, int* __restrict__ ndeg,
    int n)
{
    __shared__ int cnt[256], st[256], cur[256];
    const int b    = blockIdx.x;
    const int tid  = threadIdx.x;
    const int nbase = b << BSH;
    const int base = bstart[b];
    const int bcnt = bcount[b];

    if (tid < 256) cnt[tid] = 0;
    __syncthreads();

    for (int i = tid; i < bcnt; i += 1024)
        atomicAdd(&cnt[dl8[base + i]], 1);
    __syncthreads();

    if (tid < 64) {
        int c0 = cnt[4 * tid], c1 = cnt[4 * tid + 1];
        int c2 = cnt[4 * tid + 2], c3 = cnt[4 * tid + 3];
        int s = c0 + c1 + c2 + c3;
        int incl = s;
        #pragma unroll
        for (int off = 1; off < 64; off <<= 1) {
            int u = __shfl_up(incl, off, 64);
            if (tid >= off) incl += u;
        }
        int run = incl - s;
        st[4 * tid    ] = run; cur[4 * tid    ] = run; run += c0;
        st[4 * tid + 1] = run; cur[4 * tid + 1] = run; run += c1;
        st[4 * tid + 2] = run; cur[4 * tid + 2] = run; run += c2;
        st[4 * tid + 3] = run; cur[4 * tid + 3] = run;
    }
    __syncthreads();

    if (tid < 256) {
        int node = nbase + tid;
        if (node < n) {
            nstart[node] = base + st[tid];
            ndeg[node]   = cnt[tid];
        }
    }

    for (int i = tid; i < bcnt; i += 1024) {
        int4 r = recs[base + i];
        int p = atomicAdd(&cur[r.w & 255], 1);
        recs2[base + p] = r;
    }
}

// ---------------------------------------------------------------------------
// Kernel 5: wave-per-node aggregation + residual + LayerNorm.
// Record addresses are wave-uniform (readfirstlane -> scalar cache),
// freeing the VMEM pipe for h-gathers.
// ---------------------------------------------------------------------------
__global__ __launch_bounds__(256) void k_agg(
    const int* __restrict__ nstart, const int* __restrict__ ndeg,
    const int4* __restrict__ recs2, const __half* __restrict__ h16,
    const float* __restrict__ gamma, const float* __restrict__ beta,
    float* __restrict__ out, int n)
{
    int gid  = blockIdx.x * 256 + threadIdx.x;
    int node = gid >> 6;
    int lane = gid & 63;
    if (node >= n) return;
    const int hh   = lane >> 4;
    const int wsh  = (hh & 1) ? 0 : 16;   // bf16 lane-slot shift

    const unsigned rs = (unsigned)__builtin_amdgcn_readfirstlane(nstart[node]);
    const int deg     = __builtin_amdgcn_readfirstlane(ndeg[node]);
    const int4* pr = recs2 + rs;

    const float h_node = __half2float(h16[((unsigned)node << 6) | lane]);

    float sum = 0.f, accv = 0.f;

#define PROC_EDGE(HV, YW, ZW)                                            \
    {                                                                    \
        int w_ = (hh < 2) ? (YW) : (ZW);                                 \
        float wf_ = __int_as_float(((unsigned)w_ << wsh) & 0xffff0000u); \
        sum  += wf_;                                                     \
        accv += wf_ * (HV);                                              \
    }

    int i = 0;
    for (; i + 8 <= deg; i += 8) {
        int4 r[8];
        #pragma unroll
        for (int j = 0; j < 8; ++j) r[j] = pr[i + j];   // wave-uniform (SMEM)
        float hv[8];
        #pragma unroll
        for (int j = 0; j < 8; ++j)
            hv[j] = __half2float(h16[((unsigned)r[j].x << 6) | lane]);
        #pragma unroll
        for (int j = 0; j < 8; ++j) PROC_EDGE(hv[j], r[j].y, r[j].z);
    }
    for (; i < deg; ++i) {
        int4 r0 = pr[i];
        float hv0 = __half2float(h16[((unsigned)r0.x << 6) | lane]);
        PROC_EDGE(hv0, r0.y, r0.z);
    }
#undef PROC_EDGE

    float y = accv / (sum + EPS_SM) + h_node;

    float t1 = y;
    #pragma unroll
    for (int off = 32; off; off >>= 1) t1 += __shfl_xor(t1, off, 64);
    float mu = t1 * (1.f / 64.f);
    float dv = y - mu;
    float vs = dv * dv;
    #pragma unroll
    for (int off = 32; off; off >>= 1) vs += __shfl_xor(vs, off, 64);
    float var = vs * (1.f / 64.f);
    out[((unsigned)node << 6) | lane] =
        dv * rsqrtf(var + EPS_LN) * gamma[lane] + beta[lane];
}

// ---------------------------------------------------------------------------
extern "C" void kernel_launch(void* const* d_in, const int* in_sizes, int n_in,
                              void* d_out, int out_size, void* d_ws, size_t ws_size,
                              hipStream_t stream)
{
    const float* x     = (const float*)d_in[0];
    const int*   ei    = (const int*)  d_in[1];
    const float* ea    = (const float*)d_in[2];
    const float* Wn    = (const float*)d_in[3];
    const float* We    = (const float*)d_in[4];
    const float* asrcW = (const float*)d_in[5];
    const float* adstW = (const float*)d_in[6];
    const float* gamma = (const float*)d_in[7];
    const float* beta  = (const float*)d_in[8];
    float* out = (float*)d_out;

    const int n = in_sizes[0] / 64;
    const int E = in_sizes[1] / 2;
    const int* src = ei;
    const int* dst = ei + E;
    const int NB = (n + 255) >> BSH;
    const int nchunk  = (E + CHUNK  - 1) / CHUNK;
    const int nesc    = nchunk;
    const int nchunk1 = (E + CHUNK1 - 1) / CHUNK1;
    const int nbNode = (n + 63) / 64;

    float* ws = (float*)d_ws;
    size_t off = 0;
    __half* h16  = (__half*)(ws + off); off += (size_t)n * 32;   // n*64 halves
    float* a_src = ws + off; off += (size_t)n * 4;
    float* a_dst = ws + off; off += (size_t)n * 4;
    int4* recs   = (int4*)(ws + off); off += (size_t)E * 4;
    int4* recs2  = (int4*)(ws + off); off += (size_t)E * 4;
    __half* esc16 = (__half*)(ws + off); off += (size_t)E * 2;   // E*4 halves
    unsigned char* dl8 = (unsigned char*)(ws + off); off += ((size_t)E + 3) / 4;
    int* ibase  = (int*)(ws + off);
    int* gbcnt  = ibase;                       // NBMAX*PAD
    int* bcur   = ibase + NBMAX * PAD;         // NBMAX*PAD
    int* bstart = ibase + 2 * NBMAX * PAD;     // NBMAX
    int* bcount = bstart + NBMAX;              // NBMAX
    int* nstart = bcount + NBMAX;              // n
    int* ndeg   = nstart + n;                  // n

    hipMemsetAsync(gbcnt, 0, (size_t)NBMAX * PAD * sizeof(int), stream);

    k_node_hist_esc<<<nbNode + nchunk + nesc, 256, 0, stream>>>(
        x, Wn, asrcW, adstW, h16, a_src, a_dst, n, dst, gbcnt, E,
        nbNode, nchunk, ea, We, esc16);
    k_bscan<<<1, 64, 0, stream>>>(gbcnt, bstart, bcount, bcur);
    k_pass1<<<nchunk1, 512, 0, stream>>>(src, dst, esc16, a_src, a_dst,
                                         bcur, recs, dl8, E);
    k_bin<<<NB, 1024, 0, stream>>>(bstart, bcount, recs, dl8, recs2,
                                   nstart, ndeg, n);
    k_agg<<<((size_t)n * 64 + 255) / 256, 256, 0, stream>>>(
        nstart, ndeg, recs2, h16, gamma, beta, out, n);
}

// Round 19
// 183.434 us; speedup vs baseline: 1.0115x; 1.0115x over previous
//
#include <hip/hip_runtime.h>
#include <hip/hip_fp16.h>
#include <math.h>

#define NEG_SLOPE 0.2f
#define EPS_SM 1e-8f
#define EPS_LN 1e-5f
#define PAD 16          // one global counter per 64B line
#define BSH 8           // bucket = dst >> 8  (256 nodes/bucket)
#define NBMAX 512       // max buckets (n <= 131072)
#define CHUNK 2048      // edges per bhist/esc block
#define CHUNK1 1024     // edges per pass1 block (512 thr x 2 edges)

// round-to-nearest bf16 pair pack: returns (bf16(b)<<16) | bf16(a)
__device__ inline unsigned bf16pair(float a, float b)
{
    unsigned ua = __float_as_uint(a), ub = __float_as_uint(b);
    ua = (ua + 0x7fffu + ((ua >> 16) & 1u)) >> 16;
    ub = (ub + 0x7fffu + ((ub >> 16) & 1u)) >> 16;
    return ua | (ub << 16);
}

// ---------------------------------------------------------------------------
// Kernel 1 (triple-fused, 256 thr):
//  blocks [0, nbNode):                 h = x @ W_node + a_src/a_dst projections
//  blocks [nbNode, nbNode+nchunk):     bucket histogram over dst
//  blocks [nbNode+nchunk, +nesc):      esc16 = ea @ W_edge  (pure stream, f16x4)
// The esc stream (BW-bound) co-schedules with the GEMM blocks (VALU-bound).
// ---------------------------------------------------------------------------
__global__ __launch_bounds__(256) void k_node_hist_esc(
    const float* __restrict__ x, const float* __restrict__ Wn,
    const float* __restrict__ attn_src, const float* __restrict__ attn_dst,
    __half* __restrict__ h16, float* __restrict__ a_src, float* __restrict__ a_dst,
    int n, const int* __restrict__ dst, int* __restrict__ gbcnt, int E,
    int nbNode, int nchunk,
    const float* __restrict__ ea, const float* __restrict__ We,
    __half* __restrict__ esc16)
{
    __shared__ float Ws[64][64];   // W[k][col]  (hist: cnt[]; esc: Wes[])
    __shared__ float xs[64][64];   // x[r][k]
    const int tid = threadIdx.x;

    if (blockIdx.x >= nbNode + nchunk) {
        // ---- esc stream branch: esc16[e] = f16x4(ea[e] @ We) ----
        float* Wes = (float*)Ws;
        if (tid < 64) Wes[tid] = We[tid];
        __syncthreads();
        const int e0 = (blockIdx.x - nbNode - nchunk) * CHUNK;
        const int ce = min(CHUNK, E - e0);
        for (int j = tid; j < ce; j += 256) {
            int e = e0 + j;
            const float4* ea4 = (const float4*)(ea + (size_t)e * 16);
            float4 q0 = ea4[0], q1 = ea4[1], q2 = ea4[2], q3 = ea4[3];
            float eav[16] = {q0.x, q0.y, q0.z, q0.w, q1.x, q1.y, q1.z, q1.w,
                             q2.x, q2.y, q2.z, q2.w, q3.x, q3.y, q3.z, q3.w};
            float esc[4] = {0.f, 0.f, 0.f, 0.f};
            #pragma unroll
            for (int k = 0; k < 16; ++k) {
                #pragma unroll
                for (int hh = 0; hh < 4; ++hh) esc[hh] += eav[k] * Wes[k * 4 + hh];
            }
            __half2 p01 = __floats2half2_rn(esc[0], esc[1]);
            __half2 p23 = __floats2half2_rn(esc[2], esc[3]);
            uint2 pk = make_uint2(*reinterpret_cast<unsigned*>(&p01),
                                  *reinterpret_cast<unsigned*>(&p23));
            *(uint2*)&esc16[(size_t)e * 4] = pk;
        }
        return;
    }

    if (blockIdx.x >= nbNode) {
        // ---- bucket histogram branch ----
        int* cnt = (int*)Ws;
        for (int i = tid; i < NBMAX; i += 256) cnt[i] = 0;
        __syncthreads();
        const int e0 = (blockIdx.x - nbNode) * CHUNK;
        const int ce = min(CHUNK, E - e0);
        for (int j = tid; j < ce; j += 256)
            atomicAdd(&cnt[((unsigned)dst[e0 + j]) >> BSH], 1);
        __syncthreads();
        for (int b = tid; b < NBMAX; b += 256)
            if (cnt[b] > 0) atomicAdd(&gbcnt[b * PAD], cnt[b]);
        return;
    }

    // ---- node GEMM branch ----
    const int row0 = blockIdx.x * 64;

    const float4* Wn4 = (const float4*)Wn;
    #pragma unroll
    for (int i = tid; i < 1024; i += 256) {
        float4 v = Wn4[i];
        *(float4*)&Ws[i >> 4][(i & 15) * 4] = v;
    }
    const float4* x4 = (const float4*)x;
    #pragma unroll
    for (int i = tid; i < 1024; i += 256) {
        int r  = i >> 4;
        int gr = row0 + r;
        float4 v = (gr < n) ? x4[(size_t)gr * 16 + (i & 15)]
                            : make_float4(0.f, 0.f, 0.f, 0.f);
        *(float4*)&xs[r][(i & 15) * 4] = v;
    }
    __syncthreads();

    const int c4 = tid & 15;
    const int r4 = tid >> 4;

    float4 acc0 = make_float4(0.f, 0.f, 0.f, 0.f);
    float4 acc1 = make_float4(0.f, 0.f, 0.f, 0.f);
    float4 acc2 = make_float4(0.f, 0.f, 0.f, 0.f);
    float4 acc3 = make_float4(0.f, 0.f, 0.f, 0.f);

    #pragma unroll 8
    for (int k = 0; k < 64; ++k) {
        float4 w = *(const float4*)&Ws[k][c4 * 4];
        float x0 = xs[r4     ][k];
        float x1 = xs[r4 + 16][k];
        float x2 = xs[r4 + 32][k];
        float x3 = xs[r4 + 48][k];
        acc0.x += x0 * w.x; acc0.y += x0 * w.y; acc0.z += x0 * w.z; acc0.w += x0 * w.w;
        acc1.x += x1 * w.x; acc1.y += x1 * w.y; acc1.z += x1 * w.z; acc1.w += x1 * w.w;
        acc2.x += x2 * w.x; acc2.y += x2 * w.y; acc2.z += x2 * w.z; acc2.w += x2 * w.w;
        acc3.x += x3 * w.x; acc3.y += x3 * w.y; acc3.z += x3 * w.z; acc3.w += x3 * w.w;
    }

    const float4 asw = *(const float4*)&attn_src[c4 * 4];
    const float4 adw = *(const float4*)&attn_dst[c4 * 4];
    const int hh = c4 >> 2;
    const bool writer = (c4 & 3) == 0;

    float4 accs[4] = {acc0, acc1, acc2, acc3};
    #pragma unroll
    for (int j = 0; j < 4; ++j) {
        int gr = row0 + r4 + 16 * j;
        if (gr < n) {
            __half2 p0 = __floats2half2_rn(accs[j].x, accs[j].y);
            __half2 p1 = __floats2half2_rn(accs[j].z, accs[j].w);
            uint2 pk = make_uint2(*reinterpret_cast<unsigned*>(&p0),
                                  *reinterpret_cast<unsigned*>(&p1));
            *(uint2*)&h16[(size_t)gr * 64 + c4 * 4] = pk;
            float ps = accs[j].x * asw.x + accs[j].y * asw.y +
                       accs[j].z * asw.z + accs[j].w * asw.w;
            float pd = accs[j].x * adw.x + accs[j].y * adw.y +
                       accs[j].z * adw.z + accs[j].w * adw.w;
            ps += __shfl_xor(ps, 1, 64); ps += __shfl_xor(ps, 2, 64);
            pd += __shfl_xor(pd, 1, 64); pd += __shfl_xor(pd, 2, 64);
            if (writer) {
                a_src[(size_t)gr * 4 + hh] = ps;
                a_dst[(size_t)gr * 4 + hh] = pd;
            }
        } else {
            float ps = 0.f, pd = 0.f;
            ps += __shfl_xor(ps, 1, 64); ps += __shfl_xor(ps, 2, 64);
            pd += __shfl_xor(pd, 1, 64); pd += __shfl_xor(pd, 2, 64);
        }
    }
}

// ---------------------------------------------------------------------------
// Kernel 2: exclusive scan of 512 bucket counts (one wave).
// ---------------------------------------------------------------------------
__global__ void k_bscan(const int* __restrict__ gbcnt,
                        int* __restrict__ bstart, int* __restrict__ bcount,
                        int* __restrict__ bcur)
{
    int lane = threadIdx.x;   // 64 threads
    int c[8]; int s = 0;
    #pragma unroll
    for (int j = 0; j < 8; ++j) { c[j] = gbcnt[(lane * 8 + j) * PAD]; s += c[j]; }
    int incl = s;
    #pragma unroll
    for (int off = 1; off < 64; off <<= 1) {
        int u = __shfl_up(incl, off, 64);
        if (lane >= off) incl += u;
    }
    int run = incl - s;
    #pragma unroll
    for (int j = 0; j < 8; ++j) {
        int b = lane * 8 + j;
        bstart[b] = run;
        bcount[b] = c[j];
        bcur[b * PAD] = run;
        run += c[j];
    }
}

// ---------------------------------------------------------------------------
// Kernel 3: bucket-grouped scatter + weight computation from precomputed
// esc16 (NO ea stream here — reads are tiny: src/dst/esc16 + L2-hot
// a-gathers). 512 threads, 2 edges/thread. w = exp(lrelu(as+esc+ad)),
// packed bf16x4. Record: int4 { src, bf16x2(w0,w1), bf16x2(w2,w3), dst }.
// ---------------------------------------------------------------------------
__global__ __launch_bounds__(512) void k_pass1(
    const int* __restrict__ src, const int* __restrict__ dst,
    const __half* __restrict__ esc16,
    const float* __restrict__ a_src, const float* __restrict__ a_dst,
    int* __restrict__ bcur, int4* __restrict__ rec_out,
    unsigned char* __restrict__ dl8_out, int E)
{
    __shared__ int cnt[NBMAX];      // 2KB
    __shared__ int gpos[NBMAX];     // 2KB
    const int tid = threadIdx.x;
    if (tid < NBMAX) cnt[tid] = 0;
    __syncthreads();

    const int e0 = blockIdx.x * CHUNK1;
    int d[2], s[2], rk[2];
    #pragma unroll
    for (int j = 0; j < 2; ++j) {
        int e = e0 + j * 512 + tid;
        bool v = e < E;
        d[j] = v ? dst[e] : -1;
        s[j] = v ? src[e] : 0;
    }

    #pragma unroll
    for (int j = 0; j < 2; ++j)
        rk[j] = (d[j] >= 0) ? atomicAdd(&cnt[((unsigned)d[j]) >> BSH], 1) : 0;

    float4 as4[2], ad4[2];
    uint2 ev[2];
    #pragma unroll
    for (int j = 0; j < 2; ++j) {
        int e = e0 + j * 512 + tid;
        as4[j] = (d[j] >= 0) ? *(const float4*)(a_src + (size_t)s[j] * 4)
                             : make_float4(0.f, 0.f, 0.f, 0.f);
        ad4[j] = (d[j] >= 0) ? *(const float4*)(a_dst + (size_t)d[j] * 4)
                             : make_float4(0.f, 0.f, 0.f, 0.f);
        ev[j]  = (d[j] >= 0) ? *(const uint2*)&esc16[(size_t)e * 4]
                             : make_uint2(0, 0);
    }

    int ry[2], rz[2];
    #pragma unroll
    for (int j = 0; j < 2; ++j) {
        if (d[j] < 0) { ry[j] = 0; rz[j] = 0; continue; }
        float2 e01 = __half22float2(*reinterpret_cast<__half2*>(&ev[j].x));
        float2 e23 = __half22float2(*reinterpret_cast<__half2*>(&ev[j].y));
        float a0 = as4[j].x + e01.x + ad4[j].x;
        float a1 = as4[j].y + e01.y + ad4[j].y;
        float a2 = as4[j].z + e23.x + ad4[j].z;
        float a3 = as4[j].w + e23.y + ad4[j].w;
        a0 = (a0 >= 0.f) ? a0 : NEG_SLOPE * a0;
        a1 = (a1 >= 0.f) ? a1 : NEG_SLOPE * a1;
        a2 = (a2 >= 0.f) ? a2 : NEG_SLOPE * a2;
        a3 = (a3 >= 0.f) ? a3 : NEG_SLOPE * a3;
        ry[j] = (int)bf16pair(__expf(a0), __expf(a1));
        rz[j] = (int)bf16pair(__expf(a2), __expf(a3));
    }
    __syncthreads();

    if (tid < NBMAX) {
        int c = cnt[tid];
        if (c > 0) gpos[tid] = atomicAdd(&bcur[tid * PAD], c);
    }
    __syncthreads();

    #pragma unroll
    for (int j = 0; j < 2; ++j) {
        if (d[j] < 0) continue;
        int g = gpos[((unsigned)d[j]) >> BSH] + rk[j];
        rec_out[g] = make_int4(s[j], ry[j], rz[j], d[j]);
        dl8_out[g] = (unsigned char)(d[j] & 255);
    }
}

// ---------------------------------------------------------------------------
// Kernel 4: per-bucket counting sort to per-node-contiguous order (pure
// permutation — weights already in the record). Emits recs2 + nstart/ndeg.
// ---------------------------------------------------------------------------
__global__ __launch_bounds__(1024) void k_bin(
    const int* __restrict__ bstart, const int* __restrict__ bcount,
    const int4* __restrict__ recs, const unsigned char* __restrict__ dl8,
    int4* __restrict__ recs2, int* __restrict__ nstart, int* __restrict__ ndeg,
    int n)
{
    __shared__ int cnt[256], st[256], cur[256];
    const int b    = blockIdx.x;
    const int tid  = threadIdx.x;
    const int nbase = b << BSH;
    const int base = bstart[b];
    const int bcnt = bcount[b];

    if (tid < 256) cnt[tid] = 0;
    __syncthreads();

    for (int i = tid; i < bcnt; i += 1024)
        atomicAdd(&cnt[dl8[base + i]], 1);
    __syncthreads();

    if (tid < 64) {
        int c0 = cnt[4 * tid], c1 = cnt[4 * tid + 1];
        int c2 = cnt[4 * tid + 2], c3 = cnt[4 * tid + 3];
        int s = c0 + c1 + c2 + c3;
        int incl = s;
        #pragma unroll
        for (int off = 1; off < 64; off <<= 1) {
            int u = __shfl_up(incl, off, 64);
            if (tid >= off) incl += u;
        }
        int run = incl - s;
        st[4 * tid    ] = run; cur[4 * tid    ] = run; run += c0;
        st[4 * tid + 1] = run; cur[4 * tid + 1] = run; run += c1;
        st[4 * tid + 2] = run; cur[4 * tid + 2] = run; run += c2;
        st[4 * tid + 3] = run; cur[4 * tid + 3] = run;
    }
    __syncthreads();

    if (tid < 256) {
        int node = nbase + tid;
        if (node < n) {
            nstart[node] = base + st[tid];
            ndeg[node]   = cnt[tid];
        }
    }

    for (int i = tid; i < bcnt; i += 1024) {
        int4 r = recs[base + i];
        int p = atomicAdd(&cur[r.w & 255], 1);
        recs2[base + p] = r;
    }
}

// ---------------------------------------------------------------------------
// Kernel 5: wave-per-node aggregation + residual + LayerNorm.
// Record addresses are wave-uniform (readfirstlane -> scalar cache),
// freeing the VMEM pipe for h-gathers.
// ---------------------------------------------------------------------------
__global__ __launch_bounds__(256) void k_agg(
    const int* __restrict__ nstart, const int* __restrict__ ndeg,
    const int4* __restrict__ recs2, const __half* __restrict__ h16,
    const float* __restrict__ gamma, const float* __restrict__ beta,
    float* __restrict__ out, int n)
{
    int gid  = blockIdx.x * 256 + threadIdx.x;
    int node = gid >> 6;
    int lane = gid & 63;
    if (node >= n) return;
    const int hh   = lane >> 4;
    const int wsh  = (hh & 1) ? 0 : 16;   // bf16 lane-slot shift

    const unsigned rs = (unsigned)__builtin_amdgcn_readfirstlane(nstart[node]);
    const int deg     = __builtin_amdgcn_readfirstlane(ndeg[node]);
    const int4* pr = recs2 + rs;

    const float h_node = __half2float(h16[((unsigned)node << 6) | lane]);

    float sum = 0.f, accv = 0.f;

#define PROC_EDGE(HV, YW, ZW)                                            \
    {                                                                    \
        int w_ = (hh < 2) ? (YW) : (ZW);                                 \
        float wf_ = __int_as_float(((unsigned)w_ << wsh) & 0xffff0000u); \
        sum  += wf_;                                                     \
        accv += wf_ * (HV);                                              \
    }

    int i = 0;
    for (; i + 8 <= deg; i += 8) {
        int4 r[8];
        #pragma unroll
        for (int j = 0; j < 8; ++j) r[j] = pr[i + j];   // wave-uniform (SMEM)
        float hv[8];
        #pragma unroll
        for (int j = 0; j < 8; ++j)
            hv[j] = __half2float(h16[((unsigned)r[j].x << 6) | lane]);
        #pragma unroll
        for (int j = 0; j < 8; ++j) PROC_EDGE(hv[j], r[j].y, r[j].z);
    }
    for (; i < deg; ++i) {
        int4 r0 = pr[i];
        float hv0 = __half2float(h16[((unsigned)r0.x << 6) | lane]);
        PROC_EDGE(hv0, r0.y, r0.z);
    }
#undef PROC_EDGE

    float y = accv / (sum + EPS_SM) + h_node;

    float t1 = y;
    #pragma unroll
    for (int off = 32; off; off >>= 1) t1 += __shfl_xor(t1, off, 64);
    float mu = t1 * (1.f / 64.f);
    float dv = y - mu;
    float vs = dv * dv;
    #pragma unroll
    for (int off = 32; off; off >>= 1) vs += __shfl_xor(vs, off, 64);
    float var = vs * (1.f / 64.f);
    out[((unsigned)node << 6) | lane] =
        dv * rsqrtf(var + EPS_LN) * gamma[lane] + beta[lane];
}

// ---------------------------------------------------------------------------
extern "C" void kernel_launch(void* const* d_in, const int* in_sizes, int n_in,
                              void* d_out, int out_size, void* d_ws, size_t ws_size,
                              hipStream_t stream)
{
    const float* x     = (const float*)d_in[0];
    const int*   ei    = (const int*)  d_in[1];
    const float* ea    = (const float*)d_in[2];
    const float* Wn    = (const float*)d_in[3];
    const float* We    = (const float*)d_in[4];
    const float* asrcW = (const float*)d_in[5];
    const float* adstW = (const float*)d_in[6];
    const float* gamma = (const float*)d_in[7];
    const float* beta  = (const float*)d_in[8];
    float* out = (float*)d_out;

    const int n = in_sizes[0] / 64;
    const int E = in_sizes[1] / 2;
    const int* src = ei;
    const int* dst = ei + E;
    const int NB = (n + 255) >> BSH;
    const int nchunk  = (E + CHUNK  - 1) / CHUNK;
    const int nesc    = nchunk;
    const int nchunk1 = (E + CHUNK1 - 1) / CHUNK1;
    const int nbNode = (n + 63) / 64;

    float* ws = (float*)d_ws;
    size_t off = 0;
    __half* h16  = (__half*)(ws + off); off += (size_t)n * 32;   // n*64 halves
    float* a_src = ws + off; off += (size_t)n * 4;
    float* a_dst = ws + off; off += (size_t)n * 4;
    int4* recs   = (int4*)(ws + off); off += (size_t)E * 4;
    int4* recs2  = (int4*)(ws + off); off += (size_t)E * 4;
    __half* esc16 = (__half*)(ws + off); off += (size_t)E * 2;   // E*4 halves
    unsigned char* dl8 = (unsigned char*)(ws + off); off += ((size_t)E + 3) / 4;
    int* ibase  = (int*)(ws + off);
    int* gbcnt  = ibase;                       // NBMAX*PAD
    int* bcur   = ibase + NBMAX * PAD;         // NBMAX*PAD
    int* bstart = ibase + 2 * NBMAX * PAD;     // NBMAX
    int* bcount = bstart + NBMAX;              // NBMAX
    int* nstart = bcount + NBMAX;              // n
    int* ndeg   = nstart + n;                  // n

    hipMemsetAsync(gbcnt, 0, (size_t)NBMAX * PAD * sizeof(int), stream);

    k_node_hist_esc<<<nbNode + nchunk + nesc, 256, 0, stream>>>(
        x, Wn, asrcW, adstW, h16, a_src, a_dst, n, dst, gbcnt, E,
        nbNode, nchunk, ea, We, esc16);
    k_bscan<<<1, 64, 0, stream>>>(gbcnt, bstart, bcount, bcur);
    k_pass1<<<nchunk1, 512, 0, stream>>>(src, dst, esc16, a_src, a_dst,
                                         bcur, recs, dl8, E);
    k_bin<<<NB, 1024, 0, stream>>>(bstart, bcount, recs, dl8, recs2,
                                   nstart, ndeg, n);
    k_agg<<<((size_t)n * 64 + 255) / 256, 256, 0, stream>>>(
        nstart, ndeg, recs2, h16, gamma, beta, out, n);
}